// Round 3
// baseline (1050.230 us; speedup 1.0000x reference)
//
#include <hip/hip_runtime.h>
#include <hip/hip_bf16.h>

#define NB 8
#define NV 200
#define NE 40000
#define NH 128
#define NL 3
#define TILES (NE/64)   // 625

typedef __attribute__((ext_vector_type(8))) __bf16 bf16x8;
typedef __attribute__((ext_vector_type(8))) short s16x8;
typedef __attribute__((ext_vector_type(4))) float f32x4;

__device__ inline float sigmoidf_(float x){ return 1.0f/(1.0f + __expf(-x)); }

// round-to-nearest-even f32 -> bf16 bits
__device__ inline short f2b(float f){
  union{ float f; unsigned u; } v; v.f = f;
  unsigned u = v.u;
  u += 0x7fffu + ((u >> 16) & 1u);
  return (short)(u >> 16);
}
__device__ inline float b2f(short s){
  union{ unsigned u; float f; } v; v.u = ((unsigned)(unsigned short)s) << 16;
  return v.f;
}
// split x ~= hi + lo, both bf16
__device__ inline void splitb(float x, short &hi, short &lo){
  hi = f2b(x);
  lo = f2b(x - b2f(hi));
}

// ---------------- embed ----------------
__global__ __launch_bounds__(256) void k_embed_nodes(
    const float* __restrict__ x, const float* __restrict__ nW,
    const float* __restrict__ nb, float* __restrict__ xh)
{
  int i = blockIdx.x*256 + threadIdx.x;
  if (i >= NB*NV*NH) return;
  int h  = i & (NH-1);
  int bv = i >> 7;
  xh[i] = x[bv*2+0]*nW[h] + x[bv*2+1]*nW[NH+h] + nb[h];
}

__global__ __launch_bounds__(256) void k_embed_edges(
    const float* __restrict__ e, const float* __restrict__ eW,
    const float* __restrict__ eb, float* __restrict__ eh)
{
  int i = blockIdx.x*256 + threadIdx.x;       // over NB*NE*NH/4
  if (i >= NB*NE*NH/4) return;
  int h4 = i & (NH/4 - 1);
  int be = i >> 5;
  float ev = e[be];
  f32x4 w  = *(const f32x4*)(eW + h4*4);
  f32x4 bb = *(const f32x4*)(eb + h4*4);
  f32x4 r;
  #pragma unroll
  for (int j=0;j<4;j++) r[j] = ev*w[j] + bb[j];
  *(f32x4*)(eh + (size_t)be*NH + h4*4) = r;
}

// ---------------- weight transpose to split bf16 (Wt[n][k] = W[k][n]) ----------------
// layout: Wt + m*NH*NH        -> hi of matrix m   (m = 0..2: A_W layers, 3: out_W1)
//         Wt + (4+m)*NH*NH    -> lo of matrix m
__global__ __launch_bounds__(256) void k_trans_w(
    const float* __restrict__ AW, const float* __restrict__ oW1,
    short* __restrict__ Wt)
{
  int m = blockIdx.x;                         // 0..3
  const float* src = (m < 3) ? (AW + m*NH*NH) : oW1;
  short* dhi = Wt + (size_t)m*NH*NH;
  short* dlo = Wt + (size_t)(4+m)*NH*NH;
  for (int i = threadIdx.x; i < NH*NH; i += 256){
    int n = i >> 7, k = i & 127;
    short hi, lo;
    splitb(src[k*NH + n], hi, lo);
    dhi[i] = hi; dlo[i] = lo;
  }
}

// ---------------- CSR build ----------------
__global__ __launch_bounds__(256) void k_zero(int* __restrict__ p, int n){
  int i = blockIdx.x*256 + threadIdx.x;
  if (i < n) p[i] = 0;
}

__global__ __launch_bounds__(256) void k_count(const int* __restrict__ ei, int* __restrict__ counts){
  int i = blockIdx.x*256 + threadIdx.x;
  if (i >= NB*NE) return;
  int b = i / NE, e = i % NE;
  int dv = ei[b*2*NE + NE + e];
  atomicAdd(&counts[b*NV + dv], 1);
}

__global__ void k_scan(const int* __restrict__ counts, int* __restrict__ offs, int* __restrict__ cursor){
  int b = blockIdx.x;
  if (threadIdx.x == 0){
    int run = 0;
    for (int v=0; v<NV; v++){
      offs[b*(NV+1)+v] = run;
      cursor[b*NV+v]   = run;
      run += counts[b*NV+v];
    }
    offs[b*(NV+1)+NV] = run;
  }
}

__global__ __launch_bounds__(256) void k_scatter(const int* __restrict__ ei, int* __restrict__ cursor, int* __restrict__ csr){
  int i = blockIdx.x*256 + threadIdx.x;
  if (i >= NB*NE) return;
  int b = i / NE, e = i % NE;
  int dv = ei[b*2*NE + NE + e];
  int pos = atomicAdd(&cursor[b*NV + dv], 1);
  csr[(size_t)b*NE + pos] = e;
}

// ---------------- per-layer node matmuls: vx,bx,cx,ux ----------------
__global__ __launch_bounds__(256) void k_node_mm(
    const float* __restrict__ xh,
    const float* __restrict__ VWl, const float* __restrict__ Vbl,
    const float* __restrict__ BWl, const float* __restrict__ Bbl,
    const float* __restrict__ CWl, const float* __restrict__ Cbl,
    const float* __restrict__ UWl, const float* __restrict__ Ubl,
    float* __restrict__ vx, float* __restrict__ bx,
    float* __restrict__ cx, float* __restrict__ ux)
{
  __shared__ float sx[NH];
  int b = blockIdx.x / NV, v = blockIdx.x % NV;
  const float* xr = xh + ((size_t)b*NV + v)*NH;
  if (threadIdx.x < NH) sx[threadIdx.x] = xr[threadIdx.x];
  __syncthreads();
  #pragma unroll
  for (int pass=0; pass<2; pass++){
    int t = threadIdx.x + pass*256;
    int mat = t >> 7, h = t & 127;
    const float* W = (mat==0) ? VWl : (mat==1) ? BWl : (mat==2) ? CWl : UWl;
    const float* bs = (mat==0) ? Vbl : (mat==1) ? Bbl : (mat==2) ? Cbl : Ubl;
    float* op = (mat==0) ? vx : (mat==1) ? bx : (mat==2) ? cx : ux;
    float acc = bs[h];
    #pragma unroll 8
    for (int k=0;k<NH;k++) acc += sx[k]*W[k*NH + h];
    op[((size_t)b*NV + v)*NH + h] = acc;
  }
}

// ---------------- aggregation: agg[v] = sum_{e: dst=v} sigmoid(eh[e]) * vx[src[e]] ----------------
__global__ __launch_bounds__(128) void k_agg(
    const float* __restrict__ eh, const float* __restrict__ vx,
    const int* __restrict__ ei, const int* __restrict__ csr,
    const int* __restrict__ offs, float* __restrict__ agg)
{
  int b = blockIdx.x / NV, v = blockIdx.x % NV;
  int h = threadIdx.x;
  const int* srcp  = ei + b*2*NE;
  const int* csrg  = csr + (size_t)b*NE;
  const float* ehg = eh + (size_t)b*NE*NH;
  const float* vxg = vx + (size_t)b*NV*NH;
  int i = offs[b*(NV+1)+v], end = offs[b*(NV+1)+v+1];
  float acc = 0.f;
  for (; i+4 <= end; i += 4){
    int e0=csrg[i], e1=csrg[i+1], e2=csrg[i+2], e3=csrg[i+3];
    int s0=srcp[e0], s1=srcp[e1], s2=srcp[e2], s3=srcp[e3];
    float a0=ehg[(size_t)e0*NH+h], a1=ehg[(size_t)e1*NH+h];
    float a2=ehg[(size_t)e2*NH+h], a3=ehg[(size_t)e3*NH+h];
    float w0=vxg[s0*NH+h], w1=vxg[s1*NH+h], w2=vxg[s2*NH+h], w3=vxg[s3*NH+h];
    acc += sigmoidf_(a0)*w0 + sigmoidf_(a1)*w1 + sigmoidf_(a2)*w2 + sigmoidf_(a3)*w3;
  }
  for (; i < end; i++){
    int e0=csrg[i]; int s0=srcp[e0];
    acc += sigmoidf_(ehg[(size_t)e0*NH+h]) * vxg[s0*NH+h];
  }
  agg[((size_t)b*NV + v)*NH + h] = acc;
}

// ---------------- edge update: eh += relu(eh@A_W + A_b + bx[src] + cx[dst]) ----------------
__global__ __launch_bounds__(256) void k_edge_update(
    float* __restrict__ eh, const short* __restrict__ Wt,
    const float* __restrict__ Ab, const float* __restrict__ bx,
    const float* __restrict__ cx, const int* __restrict__ ei)
{
  int tile = blockIdx.x % TILES;
  int b    = blockIdx.x / TILES;
  int wave = threadIdx.x >> 6;
  int lane = threadIdx.x & 63;
  int l15 = lane & 15, lg = lane >> 4;
  int e0 = tile*64 + wave*16;
  float* ehg = eh + (size_t)b*NE*NH;
  const short* Whi = Wt;
  const short* Wlo = Wt + 4*NH*NH;

  // A fragments (split): row = l15 (edge), k = kk*32 + lg*8 + j (same map as B)
  const float* aptr = ehg + (size_t)(e0 + l15)*NH + lg*8;
  bf16x8 ah[4], al[4];
  #pragma unroll
  for (int kk=0;kk<4;kk++){
    f32x4 lo4 = *(const f32x4*)(aptr + kk*32);
    f32x4 hi4 = *(const f32x4*)(aptr + kk*32 + 4);
    union{ short s[8]; bf16x8 v; } uh, ul;
    #pragma unroll
    for (int j=0;j<4;j++){
      splitb(lo4[j], uh.s[j],   ul.s[j]);
      splitb(hi4[j], uh.s[4+j], ul.s[4+j]);
    }
    ah[kk] = uh.v; al[kk] = ul.v;
  }

  f32x4 acc[8];
  #pragma unroll
  for (int n=0;n<8;n++) acc[n] = (f32x4){0.f,0.f,0.f,0.f};

  #pragma unroll
  for (int kk=0;kk<4;kk++){
    #pragma unroll
    for (int n=0;n<8;n++){
      int wo = (n*16 + l15)*NH + kk*32 + lg*8;
      union{ s16x8 s; bf16x8 v; } bh, bl;
      bh.s = *(const s16x8*)(Whi + wo);
      bl.s = *(const s16x8*)(Wlo + wo);
      acc[n] = __builtin_amdgcn_mfma_f32_16x16x32_bf16(ah[kk], bh.v, acc[n], 0, 0, 0);
      acc[n] = __builtin_amdgcn_mfma_f32_16x16x32_bf16(al[kk], bh.v, acc[n], 0, 0, 0);
      acc[n] = __builtin_amdgcn_mfma_f32_16x16x32_bf16(ah[kk], bl.v, acc[n], 0, 0, 0);
    }
  }

  // epilogue: C row = lg*4 + r (edge), col = n*16 + l15 (h)   [m89-verified]
  const int* srcp = ei + b*2*NE;
  const int* dstp = srcp + NE;
  #pragma unroll
  for (int r=0;r<4;r++){
    int er = e0 + lg*4 + r;
    int sv = srcp[er], dv = dstp[er];
    const float* bxr = bx + ((size_t)b*NV + sv)*NH;
    const float* cxr = cx + ((size_t)b*NV + dv)*NH;
    float* ehr = ehg + (size_t)er*NH;
    #pragma unroll
    for (int n=0;n<8;n++){
      int h = n*16 + l15;
      float vv = acc[n][r] + Ab[h] + bxr[h] + cxr[h];
      vv = vv > 0.f ? vv : 0.f;
      ehr[h] += vv;
    }
  }
}

// ---------------- node update: xh += relu(ux + agg) ----------------
__global__ __launch_bounds__(256) void k_node_update(
    float* __restrict__ xh, const float* __restrict__ ux, const float* __restrict__ agg)
{
  int i = blockIdx.x*256 + threadIdx.x;
  if (i >= NB*NV*NH) return;
  float u = ux[i] + agg[i];
  xh[i] += u > 0.f ? u : 0.f;
}

// ---------------- output: sigmoid(relu(eh@W1+b1)@W2+b2) ----------------
// NOTE: takes the BASE Wt pointer; indexes matrix 3 (hi) / 7 (lo) internally.
__global__ __launch_bounds__(256) void k_out(
    const float* __restrict__ eh, const short* __restrict__ Wt,
    const float* __restrict__ b1, const float* __restrict__ W2,
    const float* __restrict__ b2, float* __restrict__ out)
{
  int tile = blockIdx.x % TILES;
  int b    = blockIdx.x / TILES;
  int wave = threadIdx.x >> 6;
  int lane = threadIdx.x & 63;
  int l15 = lane & 15, lg = lane >> 4;
  int e0 = tile*64 + wave*16;
  const float* ehg = eh + (size_t)b*NE*NH;
  const short* Whi = Wt + 3*NH*NH;
  const short* Wlo = Wt + 7*NH*NH;

  const float* aptr = ehg + (size_t)(e0 + l15)*NH + lg*8;
  bf16x8 ah[4], al[4];
  #pragma unroll
  for (int kk=0;kk<4;kk++){
    f32x4 lo4 = *(const f32x4*)(aptr + kk*32);
    f32x4 hi4 = *(const f32x4*)(aptr + kk*32 + 4);
    union{ short s[8]; bf16x8 v; } uh, ul;
    #pragma unroll
    for (int j=0;j<4;j++){
      splitb(lo4[j], uh.s[j],   ul.s[j]);
      splitb(hi4[j], uh.s[4+j], ul.s[4+j]);
    }
    ah[kk] = uh.v; al[kk] = ul.v;
  }

  f32x4 acc[8];
  #pragma unroll
  for (int n=0;n<8;n++) acc[n] = (f32x4){0.f,0.f,0.f,0.f};
  #pragma unroll
  for (int kk=0;kk<4;kk++){
    #pragma unroll
    for (int n=0;n<8;n++){
      int wo = (n*16 + l15)*NH + kk*32 + lg*8;
      union{ s16x8 s; bf16x8 v; } bh, bl;
      bh.s = *(const s16x8*)(Whi + wo);
      bl.s = *(const s16x8*)(Wlo + wo);
      acc[n] = __builtin_amdgcn_mfma_f32_16x16x32_bf16(ah[kk], bh.v, acc[n], 0, 0, 0);
      acc[n] = __builtin_amdgcn_mfma_f32_16x16x32_bf16(al[kk], bh.v, acc[n], 0, 0, 0);
      acc[n] = __builtin_amdgcn_mfma_f32_16x16x32_bf16(ah[kk], bl.v, acc[n], 0, 0, 0);
    }
  }

  float p0[4] = {0.f,0.f,0.f,0.f};
  float p1[4] = {0.f,0.f,0.f,0.f};
  #pragma unroll
  for (int n=0;n<8;n++){
    int h = n*16 + l15;
    float bb = b1[h];
    float w20 = W2[h*2+0], w21 = W2[h*2+1];
    #pragma unroll
    for (int r=0;r<4;r++){
      float hv = acc[n][r] + bb;
      hv = hv > 0.f ? hv : 0.f;
      p0[r] += hv*w20;
      p1[r] += hv*w21;
    }
  }
  #pragma unroll
  for (int m=1;m<16;m<<=1){
    #pragma unroll
    for (int r=0;r<4;r++){
      p0[r] += __shfl_xor(p0[r], m, 64);
      p1[r] += __shfl_xor(p1[r], m, 64);
    }
  }
  if (l15 == 0){
    float bb0 = b2[0], bb1 = b2[1];
    #pragma unroll
    for (int r=0;r<4;r++){
      int er = e0 + lg*4 + r;
      out[((size_t)b*NE + er)*2 + 0] = sigmoidf_(p0[r] + bb0);
      out[((size_t)b*NE + er)*2 + 1] = sigmoidf_(p1[r] + bb1);
    }
  }
}

extern "C" void kernel_launch(void* const* d_in, const int* in_sizes, int n_in,
                              void* d_out, int out_size, void* d_ws, size_t ws_size,
                              hipStream_t stream)
{
  const float* x   = (const float*)d_in[0];
  const float* e   = (const float*)d_in[1];
  const int*   ei  = (const int*)d_in[2];
  const float* nW  = (const float*)d_in[3];
  const float* nb  = (const float*)d_in[4];
  const float* eW  = (const float*)d_in[5];
  const float* eb  = (const float*)d_in[6];
  const float* UW  = (const float*)d_in[7];
  const float* Ub  = (const float*)d_in[8];
  const float* VW  = (const float*)d_in[9];
  const float* Vb  = (const float*)d_in[10];
  const float* AW  = (const float*)d_in[11];
  const float* Ab  = (const float*)d_in[12];
  const float* BW  = (const float*)d_in[13];
  const float* Bb  = (const float*)d_in[14];
  const float* CW  = (const float*)d_in[15];
  const float* Cb  = (const float*)d_in[16];
  const float* oW1 = (const float*)d_in[17];
  const float* ob1 = (const float*)d_in[18];
  const float* oW2 = (const float*)d_in[19];
  const float* ob2 = (const float*)d_in[20];
  float* out = (float*)d_out;

  char* ws = (char*)d_ws;
  size_t off = 0;
  auto alloc = [&](size_t bytes)->char*{
    char* p = ws + off;
    off += (bytes + 255) & ~(size_t)255;
    return p;
  };
  float* eh     = (float*)alloc((size_t)NB*NE*NH*4);
  float* xh     = (float*)alloc((size_t)NB*NV*NH*4);
  float* vx     = (float*)alloc((size_t)NB*NV*NH*4);
  float* bx     = (float*)alloc((size_t)NB*NV*NH*4);
  float* cx     = (float*)alloc((size_t)NB*NV*NH*4);
  float* ux     = (float*)alloc((size_t)NB*NV*NH*4);
  float* agg    = (float*)alloc((size_t)NB*NV*NH*4);
  short* Wt     = (short*)alloc((size_t)8*NH*NH*2);
  int* counts   = (int*)alloc((size_t)NB*NV*4);
  int* cursor   = (int*)alloc((size_t)NB*NV*4);
  int* offs     = (int*)alloc((size_t)NB*(NV+1)*4);
  int* csr      = (int*)alloc((size_t)NB*NE*4);
  (void)ws_size; (void)in_sizes; (void)n_in; (void)out_size;

  k_embed_nodes<<<(NB*NV*NH+255)/256, 256, 0, stream>>>(x, nW, nb, xh);
  k_embed_edges<<<(NB*NE*NH/4+255)/256, 256, 0, stream>>>(e, eW, eb, eh);
  k_trans_w<<<4, 256, 0, stream>>>(AW, oW1, Wt);
  k_zero<<<(NB*NV+255)/256, 256, 0, stream>>>(counts, NB*NV);
  k_count<<<(NB*NE+255)/256, 256, 0, stream>>>(ei, counts);
  k_scan<<<NB, 64, 0, stream>>>(counts, offs, cursor);
  k_scatter<<<(NB*NE+255)/256, 256, 0, stream>>>(ei, cursor, csr);

  for (int l=0; l<NL; l++){
    k_node_mm<<<NB*NV, 256, 0, stream>>>(xh,
        VW + l*NH*NH, Vb + l*NH, BW + l*NH*NH, Bb + l*NH,
        CW + l*NH*NH, Cb + l*NH, UW + l*NH*NH, Ub + l*NH,
        vx, bx, cx, ux);
    k_agg<<<NB*NV, 128, 0, stream>>>(eh, vx, ei, csr, offs, agg);
    k_edge_update<<<NB*TILES, 256, 0, stream>>>(eh, Wt + l*NH*NH, Ab + l*NH, bx, cx, ei);
    k_node_update<<<(NB*NV*NH+255)/256, 256, 0, stream>>>(xh, ux, agg);
  }
  k_out<<<NB*TILES, 256, 0, stream>>>(eh, Wt, ob1, oW2, ob2, out);
}